// Round 7
// baseline (623.361 us; speedup 1.0000x reference)
//
#include <hip/hip_runtime.h>

#define N_NODES 50000
#define N_EDGES 800000
#define IN_F 96
#define H_F 256
#define N_NIE 4
#define SCAN_NB 196   // ceil(50000/256)
#define SCAT_NP 4     // scatter window passes
#define SCAT_W 12500  // rows per window

typedef float f32x4 __attribute__((ext_vector_type(4)));
typedef short s16x8 __attribute__((ext_vector_type(8)));
typedef unsigned short u16x4 __attribute__((ext_vector_type(4)));
typedef unsigned short ushort;

__device__ __forceinline__ ushort bf16_rne(float f) {
    unsigned u = __float_as_uint(f);
    u += 0x7fffu + ((u >> 16) & 1u);
    return (ushort)(u >> 16);
}
__device__ __forceinline__ float bf16_f(ushort h) {
    return __uint_as_float(((unsigned)h) << 16);
}

// ---------------- CSR build ----------------
__global__ __launch_bounds__(256) void k_count(const int* __restrict__ rows,
                                               const int* __restrict__ cols,
                                               int* __restrict__ cnt) {
    int i = blockIdx.x * 256 + threadIdx.x;
    if (i >= N_EDGES / 2) return;
    int2 r2 = ((const int2*)rows)[i];
    int2 c2 = ((const int2*)cols)[i];
    if (r2.x != c2.x) atomicAdd(&cnt[r2.x], 1);
    if (r2.y != c2.y) atomicAdd(&cnt[r2.y], 1);
}

__global__ __launch_bounds__(256) void k_scan1(const int* __restrict__ cnt,
                                               int* __restrict__ rowptr,
                                               int* __restrict__ bsum) {
    __shared__ int s[256];
    int t = threadIdx.x, e = blockIdx.x * 256 + t;
    int v = (e < N_NODES) ? cnt[e] : 0;
    s[t] = v;
    __syncthreads();
    #pragma unroll
    for (int off = 1; off < 256; off <<= 1) {
        int nv = (t >= off) ? s[t - off] : 0;
        __syncthreads();
        s[t] += nv;
        __syncthreads();
    }
    if (e < N_NODES) rowptr[e] = s[t] - v;
    if (t == 255) bsum[blockIdx.x] = s[255];
}

__global__ __launch_bounds__(256) void k_scan2(int* __restrict__ bsum,
                                               int* __restrict__ boff,
                                               int* __restrict__ rowptr) {
    __shared__ int s[256];
    int t = threadIdx.x;
    int v = (t < SCAN_NB) ? bsum[t] : 0;
    s[t] = v;
    __syncthreads();
    #pragma unroll
    for (int off = 1; off < 256; off <<= 1) {
        int nv = (t >= off) ? s[t - off] : 0;
        __syncthreads();
        s[t] += nv;
        __syncthreads();
    }
    if (t < SCAN_NB) boff[t] = s[t] - v;
    if (t == 255) rowptr[N_NODES] = s[255];
}

// phase 3 + dinv fused
__global__ __launch_bounds__(256) void k_scan3(const int* __restrict__ boff,
                                               const int* __restrict__ cnt,
                                               int* __restrict__ rowptr,
                                               int* __restrict__ cursor,
                                               float* __restrict__ dinv) {
    int e = blockIdx.x * 256 + threadIdx.x;
    if (e >= N_NODES) return;
    int r = rowptr[e] + boff[blockIdx.x];
    rowptr[e] = r;
    cursor[e] = r;
    dinv[e] = rsqrtf((float)cnt[e] + 1.0f);
}

// windowed scatter: only rows in [rlo, rhi) this pass -> cw writes stay in a
// ~1.6 MB cache-resident window instead of 800K random touches over 6.4 MB
__global__ __launch_bounds__(256) void k_scatter(const int* __restrict__ rows,
                                                 const int* __restrict__ cols,
                                                 const float* __restrict__ dinv,
                                                 int* __restrict__ cursor,
                                                 int2* __restrict__ cw,
                                                 int rlo, int rhi) {
    int e = blockIdx.x * 256 + threadIdx.x;
    if (e >= N_EDGES) return;
    int r = rows[e];
    if (r < rlo || r >= rhi) return;
    int c = cols[e];
    if (r == c) return;  // set_diag zeroes pre-existing diagonal entries
    int p = atomicAdd(&cursor[r], 1);
    cw[p] = make_int2(c, __float_as_int(dinv[c]));
}

// ---------------- weight transpose + split ----------------
__global__ __launch_bounds__(256) void k_wsplit(const float* __restrict__ src,
                                                ushort* __restrict__ dh,
                                                ushort* __restrict__ dl,
                                                int K, int N, int total) {
    int idx = blockIdx.x * 256 + threadIdx.x;
    if (idx >= total) return;
    int kn = K * N;
    int g = idx / kn, rem = idx - g * kn;
    int k = rem / N, n = rem - k * N;
    float v = src[idx];
    ushort h = bf16_rne(v);
    ushort l = bf16_rne(v - bf16_f(h));
    int dst = g * kn + n * K + k;
    dh[dst] = h;
    dl[dst] = l;
}

// ---------------- row-normalize features ----------------
__global__ __launch_bounds__(256) void k_norm(const float* __restrict__ feat,
                                              float* __restrict__ x) {
    int wid = (blockIdx.x * 256 + threadIdx.x) >> 6;
    int lane = threadIdx.x & 63;
    if (wid >= N_NODES) return;
    const float* fr = feat + (size_t)wid * IN_F;
    float v0 = (lane < IN_F) ? fr[lane] : 0.0f;
    float v1 = (lane < IN_F - 64) ? fr[64 + lane] : 0.0f;
    float ss = v0 * v0 + v1 * v1;
    #pragma unroll
    for (int o = 32; o; o >>= 1) ss += __shfl_xor(ss, o, 64);
    float inv = 1.0f / fmaxf(sqrtf(ss), 1e-12f);
    float* xr = x + (size_t)wid * IN_F;
    if (lane < IN_F) xr[lane] = v0 * inv;
    if (lane < IN_F - 64) xr[64 + lane] = v1 * inv;
}

// ---------------- CSR SpMM: 32-lane group/row, packed (c,w), unroll 2 ----------------
__global__ __launch_bounds__(256) void k_spmm_csr(const int* __restrict__ rowptr,
                                                  const int2* __restrict__ cw,
                                                  const float* __restrict__ dinv,
                                                  const float* __restrict__ x,
                                                  float* __restrict__ y) {
    int g = (blockIdx.x * 256 + threadIdx.x) >> 5;
    if (g >= N_NODES) return;
    int l = threadIdx.x & 31;  // lane handles feats l, l+32, l+64
    float dr = dinv[g];
    const float* xg = x + (size_t)g * IN_F;
    float s0 = xg[l], s1 = xg[l + 32], s2 = xg[l + 64];
    float a0 = 0.f, a1 = 0.f, a2 = 0.f;
    float b0 = 0.f, b1 = 0.f, b2 = 0.f;
    int k = rowptr[g], e = rowptr[g + 1];
    for (; k + 1 < e; k += 2) {
        int2 p0 = cw[k], p1 = cw[k + 1];
        float w0 = __int_as_float(p0.y), w1 = __int_as_float(p1.y);
        const float* x0 = x + (size_t)p0.x * IN_F;
        const float* x1 = x + (size_t)p1.x * IN_F;
        a0 += x0[l] * w0; a1 += x0[l + 32] * w0; a2 += x0[l + 64] * w0;
        b0 += x1[l] * w1; b1 += x1[l + 32] * w1; b2 += x1[l + 64] * w1;
    }
    if (k < e) {
        int2 p0 = cw[k];
        float w0 = __int_as_float(p0.y);
        const float* x0 = x + (size_t)p0.x * IN_F;
        a0 += x0[l] * w0; a1 += x0[l + 32] * w0; a2 += x0[l + 64] * w0;
    }
    float* yr = y + (size_t)g * IN_F;
    yr[l]      = dr * (a0 + b0 + dr * s0);
    yr[l + 32] = dr * (a1 + b1 + dr * s1);
    yr[l + 64] = dr * (a2 + b2 + dr * s2);
}

// ---------------- MFMA MLP (64x64 tiles, grid (4,782)): ns = relu(A @ WsT + b) ----------------
#define LDA1 104
__global__ __launch_bounds__(256) void k_mlp_mfma(const float* __restrict__ A,
                                                   const ushort* __restrict__ BTh,
                                                   const ushort* __restrict__ BTl,
                                                   const float* __restrict__ bias,
                                                   ushort* __restrict__ nsh,
                                                   ushort* __restrict__ nsl) {
    __shared__ ushort Ah[64 * LDA1], Al[64 * LDA1], Bh[64 * LDA1], Bl[64 * LDA1];
    int m0 = blockIdx.y * 64, n0 = blockIdx.x * 64;
    int tid = threadIdx.x;
    #pragma unroll
    for (int p = 0; p < 6; ++p) {
        int flat = tid + p * 256;
        int r = flat / 24, j = flat - r * 24;
        int gm = m0 + r;
        float4 v = make_float4(0.f, 0.f, 0.f, 0.f);
        if (gm < N_NODES) v = *(const float4*)&A[(size_t)gm * IN_F + j * 4];
        float vv[4] = {v.x, v.y, v.z, v.w};
        u16x4 hh, ll;
        #pragma unroll
        for (int q = 0; q < 4; ++q) {
            ushort h = bf16_rne(vv[q]);
            hh[q] = h;
            ll[q] = bf16_rne(vv[q] - bf16_f(h));
        }
        *(u16x4*)&Ah[r * LDA1 + j * 4] = hh;
        *(u16x4*)&Al[r * LDA1 + j * 4] = ll;
    }
    #pragma unroll
    for (int p = 0; p < 3; ++p) {
        int flat = tid + p * 256;
        int r = flat / 12, j = flat - r * 12;
        *(s16x8*)&Bh[r * LDA1 + j * 8] = *(const s16x8*)&BTh[(size_t)(n0 + r) * IN_F + j * 8];
        *(s16x8*)&Bl[r * LDA1 + j * 8] = *(const s16x8*)&BTl[(size_t)(n0 + r) * IN_F + j * 8];
    }
    __syncthreads();
    int lane = tid & 63, wid = tid >> 6;
    int wr = (wid >> 1) * 32, wc = (wid & 1) * 32;
    int rsel = lane & 15, ksel = (lane >> 4) * 8;
    f32x4 acc[2][2] = {};
    #pragma unroll
    for (int ks = 0; ks < 3; ++ks) {
        int k0 = ks * 32 + ksel;
        s16x8 a0h = *(const s16x8*)&Ah[(wr + rsel) * LDA1 + k0];
        s16x8 a1h = *(const s16x8*)&Ah[(wr + 16 + rsel) * LDA1 + k0];
        s16x8 a0l = *(const s16x8*)&Al[(wr + rsel) * LDA1 + k0];
        s16x8 a1l = *(const s16x8*)&Al[(wr + 16 + rsel) * LDA1 + k0];
        s16x8 b0h = *(const s16x8*)&Bh[(wc + rsel) * LDA1 + k0];
        s16x8 b1h = *(const s16x8*)&Bh[(wc + 16 + rsel) * LDA1 + k0];
        s16x8 b0l = *(const s16x8*)&Bl[(wc + rsel) * LDA1 + k0];
        s16x8 b1l = *(const s16x8*)&Bl[(wc + 16 + rsel) * LDA1 + k0];
        acc[0][0] = __builtin_amdgcn_mfma_f32_16x16x32_bf16(a0h, b0h, acc[0][0], 0, 0, 0);
        acc[0][0] = __builtin_amdgcn_mfma_f32_16x16x32_bf16(a0h, b0l, acc[0][0], 0, 0, 0);
        acc[0][0] = __builtin_amdgcn_mfma_f32_16x16x32_bf16(a0l, b0h, acc[0][0], 0, 0, 0);
        acc[0][1] = __builtin_amdgcn_mfma_f32_16x16x32_bf16(a0h, b1h, acc[0][1], 0, 0, 0);
        acc[0][1] = __builtin_amdgcn_mfma_f32_16x16x32_bf16(a0h, b1l, acc[0][1], 0, 0, 0);
        acc[0][1] = __builtin_amdgcn_mfma_f32_16x16x32_bf16(a0l, b1h, acc[0][1], 0, 0, 0);
        acc[1][0] = __builtin_amdgcn_mfma_f32_16x16x32_bf16(a1h, b0h, acc[1][0], 0, 0, 0);
        acc[1][0] = __builtin_amdgcn_mfma_f32_16x16x32_bf16(a1h, b0l, acc[1][0], 0, 0, 0);
        acc[1][0] = __builtin_amdgcn_mfma_f32_16x16x32_bf16(a1l, b0h, acc[1][0], 0, 0, 0);
        acc[1][1] = __builtin_amdgcn_mfma_f32_16x16x32_bf16(a1h, b1h, acc[1][1], 0, 0, 0);
        acc[1][1] = __builtin_amdgcn_mfma_f32_16x16x32_bf16(a1h, b1l, acc[1][1], 0, 0, 0);
        acc[1][1] = __builtin_amdgcn_mfma_f32_16x16x32_bf16(a1l, b1h, acc[1][1], 0, 0, 0);
    }
    int crow = (lane >> 4) * 4, ccol = lane & 15;
    #pragma unroll
    for (int mf = 0; mf < 2; ++mf)
        #pragma unroll
        for (int nf = 0; nf < 2; ++nf) {
            int col = n0 + wc + nf * 16 + ccol;
            float bb = bias[col];
            #pragma unroll
            for (int i = 0; i < 4; ++i) {
                int gm = m0 + wr + mf * 16 + crow + i;
                if (gm < N_NODES) {
                    float v = fmaxf(acc[mf][nf][i] + bb, 0.f);
                    ushort h = bf16_rne(v);
                    size_t o = (size_t)gm * H_F + col;
                    nsh[o] = h;
                    nsl[o] = bf16_rne(v - bf16_f(h));
                }
            }
        }
}

// ---------------- MFMA fusion (64x64 tiles, grid (4,782)) ----------------
// MODE 0: out = acc + bias;  1: out += acc;  2: out = relu(out + acc)
#define LDA2 72
template <int MODE>
__global__ __launch_bounds__(256) void k_fuse_mfma(const ushort* __restrict__ Ahg,
                                                    const ushort* __restrict__ Alg,
                                                    const ushort* __restrict__ BTh,
                                                    const ushort* __restrict__ BTl,
                                                    const float* __restrict__ bias,
                                                    float* __restrict__ out) {
    __shared__ ushort Ah[64 * LDA2], Al[64 * LDA2], Bh[64 * LDA2], Bl[64 * LDA2];
    int m0 = blockIdx.y * 64, n0 = blockIdx.x * 64;
    int tid = threadIdx.x;
    int lane = tid & 63, wid = tid >> 6;
    int wr = (wid >> 1) * 32, wc = (wid & 1) * 32;
    int rsel = lane & 15, ksel = (lane >> 4) * 8;
    f32x4 acc[2][2] = {};
    for (int kc = 0; kc < H_F; kc += 64) {
        #pragma unroll
        for (int p = 0; p < 2; ++p) {
            int flat = tid + p * 256;  // short8 units, 8 per row
            int r = flat >> 3, j = flat & 7;
            int gm = m0 + r;
            s16x8 vh = {0, 0, 0, 0, 0, 0, 0, 0}, vl = vh;
            if (gm < N_NODES) {
                vh = *(const s16x8*)&Ahg[(size_t)gm * H_F + kc + j * 8];
                vl = *(const s16x8*)&Alg[(size_t)gm * H_F + kc + j * 8];
            }
            *(s16x8*)&Ah[r * LDA2 + j * 8] = vh;
            *(s16x8*)&Al[r * LDA2 + j * 8] = vl;
            *(s16x8*)&Bh[r * LDA2 + j * 8] = *(const s16x8*)&BTh[(size_t)(n0 + r) * H_F + kc + j * 8];
            *(s16x8*)&Bl[r * LDA2 + j * 8] = *(const s16x8*)&BTl[(size_t)(n0 + r) * H_F + kc + j * 8];
        }
        __syncthreads();
        #pragma unroll
        for (int ks = 0; ks < 2; ++ks) {
            int k0 = ks * 32 + ksel;
            s16x8 a0h = *(const s16x8*)&Ah[(wr + rsel) * LDA2 + k0];
            s16x8 a1h = *(const s16x8*)&Ah[(wr + 16 + rsel) * LDA2 + k0];
            s16x8 a0l = *(const s16x8*)&Al[(wr + rsel) * LDA2 + k0];
            s16x8 a1l = *(const s16x8*)&Al[(wr + 16 + rsel) * LDA2 + k0];
            s16x8 b0h = *(const s16x8*)&Bh[(wc + rsel) * LDA2 + k0];
            s16x8 b1h = *(const s16x8*)&Bh[(wc + 16 + rsel) * LDA2 + k0];
            s16x8 b0l = *(const s16x8*)&Bl[(wc + rsel) * LDA2 + k0];
            s16x8 b1l = *(const s16x8*)&Bl[(wc + 16 + rsel) * LDA2 + k0];
            acc[0][0] = __builtin_amdgcn_mfma_f32_16x16x32_bf16(a0h, b0h, acc[0][0], 0, 0, 0);
            acc[0][0] = __builtin_amdgcn_mfma_f32_16x16x32_bf16(a0h, b0l, acc[0][0], 0, 0, 0);
            acc[0][0] = __builtin_amdgcn_mfma_f32_16x16x32_bf16(a0l, b0h, acc[0][0], 0, 0, 0);
            acc[0][1] = __builtin_amdgcn_mfma_f32_16x16x32_bf16(a0h, b1h, acc[0][1], 0, 0, 0);
            acc[0][1] = __builtin_amdgcn_mfma_f32_16x16x32_bf16(a0h, b1l, acc[0][1], 0, 0, 0);
            acc[0][1] = __builtin_amdgcn_mfma_f32_16x16x32_bf16(a0l, b1h, acc[0][1], 0, 0, 0);
            acc[1][0] = __builtin_amdgcn_mfma_f32_16x16x32_bf16(a1h, b0h, acc[1][0], 0, 0, 0);
            acc[1][0] = __builtin_amdgcn_mfma_f32_16x16x32_bf16(a1h, b0l, acc[1][0], 0, 0, 0);
            acc[1][0] = __builtin_amdgcn_mfma_f32_16x16x32_bf16(a1l, b0h, acc[1][0], 0, 0, 0);
            acc[1][1] = __builtin_amdgcn_mfma_f32_16x16x32_bf16(a1h, b1h, acc[1][1], 0, 0, 0);
            acc[1][1] = __builtin_amdgcn_mfma_f32_16x16x32_bf16(a1h, b1l, acc[1][1], 0, 0, 0);
            acc[1][1] = __builtin_amdgcn_mfma_f32_16x16x32_bf16(a1l, b1h, acc[1][1], 0, 0, 0);
        }
        __syncthreads();
    }
    int crow = (lane >> 4) * 4, ccol = lane & 15;
    #pragma unroll
    for (int mf = 0; mf < 2; ++mf)
        #pragma unroll
        for (int nf = 0; nf < 2; ++nf) {
            int col = n0 + wc + nf * 16 + ccol;
            #pragma unroll
            for (int i = 0; i < 4; ++i) {
                int gm = m0 + wr + mf * 16 + crow + i;
                if (gm < N_NODES) {
                    float* p = &out[(size_t)gm * H_F + col];
                    if (MODE == 0) {
                        *p = acc[mf][nf][i] + bias[col];
                    } else if (MODE == 1) {
                        *p += acc[mf][nf][i];
                    } else {
                        *p = fmaxf(*p + acc[mf][nf][i], 0.f);
                    }
                }
            }
        }
}

extern "C" void kernel_launch(void* const* d_in, const int* in_sizes, int n_in,
                              void* d_out, int out_size, void* d_ws, size_t ws_size,
                              hipStream_t stream) {
    const int* ei = (const int*)d_in[0];
    const int* rows = ei;
    const int* cols = ei + N_EDGES;
    const float* feat = (const float*)d_in[1];
    const float* Ws = (const float*)d_in[2];
    const float* bs = (const float*)d_in[3];
    const float* Wf = (const float*)d_in[4];
    const float* bf = (const float*)d_in[5];
    float* out = (float*)d_out;

    // workspace layout (~97 MB, 16B-aligned chain)
    float* hA = (float*)d_ws;                              // 4,800,000 f32
    float* hB = hA + (size_t)N_NODES * IN_F;               // 4,800,000 f32
    ushort* nsh = (ushort*)(hB + (size_t)N_NODES * IN_F);  // 12,800,000 u16
    ushort* nsl = nsh + (size_t)N_NODES * H_F;             // 12,800,000 u16
    ushort* WsTh = nsl + (size_t)N_NODES * H_F;            // 98,304 u16
    ushort* WsTl = WsTh + N_NIE * IN_F * H_F;
    ushort* WfTh = WsTl + N_NIE * IN_F * H_F;              // 262,144 u16
    ushort* WfTl = WfTh + N_NIE * H_F * H_F;
    float* dinv = (float*)(WfTl + N_NIE * H_F * H_F);      // 50,000 f32
    int* rowptr = (int*)(dinv + N_NODES);                  // 50,004 i32
    int* bsum = rowptr + 50004;                            // 256 i32
    int* boff = bsum + 256;                                // 256 i32
    int2* cw = (int2*)(boff + 256);                        // 800,000 int2
    // CSR-build temporaries aliased into nsh (consumed before nsh is written)
    int* cnt = (int*)nsh;
    int* cursor = cnt + N_NODES;

    hipMemsetAsync(cnt, 0, N_NODES * sizeof(int), stream);
    k_count<<<(N_EDGES / 2 + 255) / 256, 256, 0, stream>>>(rows, cols, cnt);
    k_scan1<<<SCAN_NB, 256, 0, stream>>>(cnt, rowptr, bsum);
    k_scan2<<<1, 256, 0, stream>>>(bsum, boff, rowptr);
    k_scan3<<<SCAN_NB, 256, 0, stream>>>(boff, cnt, rowptr, cursor, dinv);
    for (int p = 0; p < SCAT_NP; ++p)
        k_scatter<<<(N_EDGES + 255) / 256, 256, 0, stream>>>(rows, cols, dinv, cursor, cw,
                                                             p * SCAT_W, (p + 1) * SCAT_W);
    k_wsplit<<<(N_NIE * IN_F * H_F + 255) / 256, 256, 0, stream>>>(Ws, WsTh, WsTl, IN_F, H_F,
                                                                   N_NIE * IN_F * H_F);
    k_wsplit<<<(N_NIE * H_F * H_F + 255) / 256, 256, 0, stream>>>(Wf, WfTh, WfTl, H_F, H_F,
                                                                  N_NIE * H_F * H_F);
    k_norm<<<(N_NODES + 3) / 4, 256, 0, stream>>>(feat, hA);

    float* hcur = hA;
    float* hnext = hB;
    for (int i = 0; i < N_NIE; ++i) {
        k_mlp_mfma<<<dim3(4, 782), 256, 0, stream>>>(hcur, WsTh + (size_t)i * IN_F * H_F,
                                                     WsTl + (size_t)i * IN_F * H_F,
                                                     bs + (size_t)i * H_F, nsh, nsl);
        const ushort* fh = WfTh + (size_t)i * H_F * H_F;
        const ushort* fl = WfTl + (size_t)i * H_F * H_F;
        if (i == 0)
            k_fuse_mfma<0><<<dim3(4, 782), 256, 0, stream>>>(nsh, nsl, fh, fl, bf, out);
        else if (i < N_NIE - 1)
            k_fuse_mfma<1><<<dim3(4, 782), 256, 0, stream>>>(nsh, nsl, fh, fl, bf, out);
        else
            k_fuse_mfma<2><<<dim3(4, 782), 256, 0, stream>>>(nsh, nsl, fh, fl, bf, out);
        if (i < N_NIE - 1) {
            k_spmm_csr<<<(N_NODES * 32 + 255) / 256, 256, 0, stream>>>(rowptr, cw, dinv,
                                                                      hcur, hnext);
            float* t = hcur; hcur = hnext; hnext = t;
        }
    }
}

// Round 8
// 563.553 us; speedup vs baseline: 1.1061x; 1.1061x over previous
//
#include <hip/hip_runtime.h>

#define N_NODES 50000
#define N_EDGES 800000
#define IN_F 96
#define H_F 256
#define N_NIE 4
#define SCAN_NB 196   // ceil(50000/256)
#define LDA1 104      // phase-1 LDS stride (shorts)
#define LDN 264       // ns_lds stride (shorts)
#define LDK2 40       // Wf-chunk LDS stride (shorts)

typedef float f32x4 __attribute__((ext_vector_type(4)));
typedef short s16x8 __attribute__((ext_vector_type(8)));
typedef unsigned short u16x4 __attribute__((ext_vector_type(4)));
typedef unsigned short ushort;

__device__ __forceinline__ ushort bf16_rne(float f) {
    unsigned u = __float_as_uint(f);
    u += 0x7fffu + ((u >> 16) & 1u);
    return (ushort)(u >> 16);
}
__device__ __forceinline__ float bf16_f(ushort h) {
    return __uint_as_float(((unsigned)h) << 16);
}

// ---------------- CSR build ----------------
__global__ __launch_bounds__(256) void k_count(const int* __restrict__ rows,
                                               const int* __restrict__ cols,
                                               int* __restrict__ cnt) {
    int i = blockIdx.x * 256 + threadIdx.x;
    if (i >= N_EDGES / 2) return;
    int2 r2 = ((const int2*)rows)[i];
    int2 c2 = ((const int2*)cols)[i];
    if (r2.x != c2.x) atomicAdd(&cnt[r2.x], 1);
    if (r2.y != c2.y) atomicAdd(&cnt[r2.y], 1);
}

__global__ __launch_bounds__(256) void k_scan1(const int* __restrict__ cnt,
                                               int* __restrict__ rowptr,
                                               int* __restrict__ bsum) {
    __shared__ int s[256];
    int t = threadIdx.x, e = blockIdx.x * 256 + t;
    int v = (e < N_NODES) ? cnt[e] : 0;
    s[t] = v;
    __syncthreads();
    #pragma unroll
    for (int off = 1; off < 256; off <<= 1) {
        int nv = (t >= off) ? s[t - off] : 0;
        __syncthreads();
        s[t] += nv;
        __syncthreads();
    }
    if (e < N_NODES) rowptr[e] = s[t] - v;
    if (t == 255) bsum[blockIdx.x] = s[255];
}

__global__ __launch_bounds__(256) void k_scan2(int* __restrict__ bsum,
                                               int* __restrict__ boff,
                                               int* __restrict__ rowptr) {
    __shared__ int s[256];
    int t = threadIdx.x;
    int v = (t < SCAN_NB) ? bsum[t] : 0;
    s[t] = v;
    __syncthreads();
    #pragma unroll
    for (int off = 1; off < 256; off <<= 1) {
        int nv = (t >= off) ? s[t - off] : 0;
        __syncthreads();
        s[t] += nv;
        __syncthreads();
    }
    if (t < SCAN_NB) boff[t] = s[t] - v;
    if (t == 255) rowptr[N_NODES] = s[255];
}

__global__ __launch_bounds__(256) void k_scan3(const int* __restrict__ boff,
                                               const int* __restrict__ cnt,
                                               int* __restrict__ rowptr,
                                               int* __restrict__ cursor,
                                               float* __restrict__ dinv) {
    int e = blockIdx.x * 256 + threadIdx.x;
    if (e >= N_NODES) return;
    int r = rowptr[e] + boff[blockIdx.x];
    rowptr[e] = r;
    cursor[e] = r;
    dinv[e] = rsqrtf((float)cnt[e] + 1.0f);
}

// single-pass scatter (R6-proven); packs (col, dinv[col])
__global__ __launch_bounds__(256) void k_scatter(const int* __restrict__ rows,
                                                 const int* __restrict__ cols,
                                                 const float* __restrict__ dinv,
                                                 int* __restrict__ cursor,
                                                 int2* __restrict__ cw) {
    int e = blockIdx.x * 256 + threadIdx.x;
    if (e >= N_EDGES) return;
    int r = rows[e], c = cols[e];
    if (r == c) return;  // set_diag zeroes pre-existing diagonal entries
    int p = atomicAdd(&cursor[r], 1);
    cw[p] = make_int2(c, __float_as_int(dinv[c]));
}

// ---------------- weight transpose + split ----------------
__global__ __launch_bounds__(256) void k_wsplit(const float* __restrict__ src,
                                                ushort* __restrict__ dh,
                                                ushort* __restrict__ dl,
                                                int K, int N, int total) {
    int idx = blockIdx.x * 256 + threadIdx.x;
    if (idx >= total) return;
    int kn = K * N;
    int g = idx / kn, rem = idx - g * kn;
    int k = rem / N, n = rem - k * N;
    float v = src[idx];
    ushort h = bf16_rne(v);
    ushort l = bf16_rne(v - bf16_f(h));
    int dst = g * kn + n * K + k;
    dh[dst] = h;
    dl[dst] = l;
}

// ---------------- row-normalize features ----------------
__global__ __launch_bounds__(256) void k_norm(const float* __restrict__ feat,
                                              float* __restrict__ x) {
    int wid = (blockIdx.x * 256 + threadIdx.x) >> 6;
    int lane = threadIdx.x & 63;
    if (wid >= N_NODES) return;
    const float* fr = feat + (size_t)wid * IN_F;
    float v0 = (lane < IN_F) ? fr[lane] : 0.0f;
    float v1 = (lane < IN_F - 64) ? fr[64 + lane] : 0.0f;
    float ss = v0 * v0 + v1 * v1;
    #pragma unroll
    for (int o = 32; o; o >>= 1) ss += __shfl_xor(ss, o, 64);
    float inv = 1.0f / fmaxf(sqrtf(ss), 1e-12f);
    float* xr = x + (size_t)wid * IN_F;
    if (lane < IN_F) xr[lane] = v0 * inv;
    if (lane < IN_F - 64) xr[64 + lane] = v1 * inv;
}

// ---------------- CSR SpMM: 32-lane group/row, packed (c,w), unroll 2 ----------------
__global__ __launch_bounds__(256) void k_spmm_csr(const int* __restrict__ rowptr,
                                                  const int2* __restrict__ cw,
                                                  const float* __restrict__ dinv,
                                                  const float* __restrict__ x,
                                                  float* __restrict__ y) {
    int g = (blockIdx.x * 256 + threadIdx.x) >> 5;
    if (g >= N_NODES) return;
    int l = threadIdx.x & 31;  // lane handles feats l, l+32, l+64
    float dr = dinv[g];
    const float* xg = x + (size_t)g * IN_F;
    float s0 = xg[l], s1 = xg[l + 32], s2 = xg[l + 64];
    float a0 = 0.f, a1 = 0.f, a2 = 0.f;
    float b0 = 0.f, b1 = 0.f, b2 = 0.f;
    int k = rowptr[g], e = rowptr[g + 1];
    for (; k + 1 < e; k += 2) {
        int2 p0 = cw[k], p1 = cw[k + 1];
        float w0 = __int_as_float(p0.y), w1 = __int_as_float(p1.y);
        const float* x0 = x + (size_t)p0.x * IN_F;
        const float* x1 = x + (size_t)p1.x * IN_F;
        a0 += x0[l] * w0; a1 += x0[l + 32] * w0; a2 += x0[l + 64] * w0;
        b0 += x1[l] * w1; b1 += x1[l + 32] * w1; b2 += x1[l + 64] * w1;
    }
    if (k < e) {
        int2 p0 = cw[k];
        float w0 = __int_as_float(p0.y);
        const float* x0 = x + (size_t)p0.x * IN_F;
        a0 += x0[l] * w0; a1 += x0[l + 32] * w0; a2 += x0[l + 64] * w0;
    }
    float* yr = y + (size_t)g * IN_F;
    yr[l]      = dr * (a0 + b0 + dr * s0);
    yr[l + 32] = dr * (a1 + b1 + dr * s1);
    yr[l + 64] = dr * (a2 + b2 + dr * s2);
}

// ---------------- MEGA: per 64-row block, loop 4 hops { ns-tile in LDS, accumulate @WfT } ----------------
// out = relu( sum_i relu(h_i @ WsT_i + bs_i) @ WfT_i + bf ), out written ONCE.
__global__ __launch_bounds__(512) void k_mega(const float* __restrict__ h0,
                                              const float* __restrict__ h1,
                                              const float* __restrict__ h2,
                                              const float* __restrict__ h3,
                                              const ushort* __restrict__ WsTh,
                                              const ushort* __restrict__ WsTl,
                                              const float* __restrict__ bs,
                                              const ushort* __restrict__ WfTh,
                                              const ushort* __restrict__ WfTl,
                                              const float* __restrict__ bf,
                                              float* __restrict__ out) {
    __shared__ ushort nsH[64 * LDN], nsL[64 * LDN];  // 67.6 KB: ns tile (split)
    __shared__ ushort U[26624];                      // 53.2 KB union region
    ushort* Ah = U;            // [64][104]
    ushort* Al = U + 6656;
    ushort* Bh = U + 13312;    // [64][104]
    ushort* Bl = U + 19968;
    ushort* Wh = U;            // [256][40] (phase 2 overlay)
    ushort* Wl = U + 10240;

    int m0 = blockIdx.x * 64;
    int tid = threadIdx.x;
    int lane = tid & 63, w = tid >> 6;
    int rsel = lane & 15, ksel = (lane >> 4) * 8;
    int crow = (lane >> 4) * 4, ccol = lane & 15;
    int rf = w & 3, cfb = (w >> 2) * 32;  // phase-1: wave owns rows rf*16.., cols cfb..
    int cw0 = w * 32;                      // phase-2: wave owns out cols cw0..cw0+31

    f32x4 acc[4][2] = {};  // persistent across hops: 64 rows x 32 cols per wave

    for (int hop = 0; hop < N_NIE; ++hop) {
        const float* A = (hop == 0) ? h0 : (hop == 1) ? h1 : (hop == 2) ? h2 : h3;
        const ushort* wsh = WsTh + hop * IN_F * H_F;  // [n=256][k=96]
        const ushort* wsl = WsTl + hop * IN_F * H_F;
        const float* bsi = bs + hop * H_F;

        // stage A rows (fp32 -> split bf16): 64 x 24 float4
        #pragma unroll
        for (int p = 0; p < 3; ++p) {
            int flat = tid + p * 512;
            int r = flat / 24, j = flat - r * 24;
            int gm = m0 + r;
            float4 v = make_float4(0.f, 0.f, 0.f, 0.f);
            if (gm < N_NODES) v = *(const float4*)&A[(size_t)gm * IN_F + j * 4];
            float vv[4] = {v.x, v.y, v.z, v.w};
            u16x4 hh, ll;
            #pragma unroll
            for (int q = 0; q < 4; ++q) {
                ushort h = bf16_rne(vv[q]);
                hh[q] = h;
                ll[q] = bf16_rne(vv[q] - bf16_f(h));
            }
            *(u16x4*)&Ah[r * LDA1 + j * 4] = hh;
            *(u16x4*)&Al[r * LDA1 + j * 4] = ll;
        }
        // ---- phase 1: ns[64][256] = relu(A @ WsT + bs) -> ns_lds (split) ----
        for (int nc = 0; nc < 4; ++nc) {
            #pragma unroll
            for (int p = 0; p < 2; ++p) {
                int flat = tid + p * 512;  // 768 short8 per array
                if (flat < 768) {
                    int r = flat / 12, j = flat - r * 12;
                    *(s16x8*)&Bh[r * LDA1 + j * 8] =
                        *(const s16x8*)&wsh[(size_t)(nc * 64 + r) * IN_F + j * 8];
                    *(s16x8*)&Bl[r * LDA1 + j * 8] =
                        *(const s16x8*)&wsl[(size_t)(nc * 64 + r) * IN_F + j * 8];
                }
            }
            __syncthreads();
            f32x4 ac[2] = {};
            #pragma unroll
            for (int ks = 0; ks < 3; ++ks) {
                int k0 = ks * 32 + ksel;
                s16x8 ah = *(const s16x8*)&Ah[(rf * 16 + rsel) * LDA1 + k0];
                s16x8 al = *(const s16x8*)&Al[(rf * 16 + rsel) * LDA1 + k0];
                #pragma unroll
                for (int cf = 0; cf < 2; ++cf) {
                    s16x8 bh = *(const s16x8*)&Bh[(cfb + cf * 16 + rsel) * LDA1 + k0];
                    s16x8 bl = *(const s16x8*)&Bl[(cfb + cf * 16 + rsel) * LDA1 + k0];
                    ac[cf] = __builtin_amdgcn_mfma_f32_16x16x32_bf16(ah, bh, ac[cf], 0, 0, 0);
                    ac[cf] = __builtin_amdgcn_mfma_f32_16x16x32_bf16(ah, bl, ac[cf], 0, 0, 0);
                    ac[cf] = __builtin_amdgcn_mfma_f32_16x16x32_bf16(al, bh, ac[cf], 0, 0, 0);
                }
            }
            #pragma unroll
            for (int cf = 0; cf < 2; ++cf) {
                int col = nc * 64 + cfb + cf * 16 + ccol;
                float bb = bsi[col];
                #pragma unroll
                for (int ii = 0; ii < 4; ++ii) {
                    int row = rf * 16 + crow + ii;
                    float v = fmaxf(ac[cf][ii] + bb, 0.f);
                    ushort h = bf16_rne(v);
                    nsH[row * LDN + col] = h;
                    nsL[row * LDN + col] = bf16_rne(v - bf16_f(h));
                }
            }
            __syncthreads();
        }
        // ---- phase 2: acc += ns @ WfT_hop ----
        const ushort* wfh = WfTh + hop * H_F * H_F;  // [n=256][k=256]
        const ushort* wfl = WfTl + hop * H_F * H_F;
        for (int kc = 0; kc < 8; ++kc) {
            #pragma unroll
            for (int p = 0; p < 4; ++p) {
                int flat = tid + p * 512;  // 1024 short8 per array
                int f2 = flat & 1023;
                int r = f2 >> 2, j = f2 & 3;
                if (flat < 1024)
                    *(s16x8*)&Wh[r * LDK2 + j * 8] =
                        *(const s16x8*)&wfh[(size_t)r * H_F + kc * 32 + j * 8];
                else
                    *(s16x8*)&Wl[r * LDK2 + j * 8] =
                        *(const s16x8*)&wfl[(size_t)r * H_F + kc * 32 + j * 8];
            }
            __syncthreads();
            int k0 = kc * 32 + ksel;
            s16x8 ah4[4], al4[4];
            #pragma unroll
            for (int mf = 0; mf < 4; ++mf) {
                ah4[mf] = *(const s16x8*)&nsH[(mf * 16 + rsel) * LDN + k0];
                al4[mf] = *(const s16x8*)&nsL[(mf * 16 + rsel) * LDN + k0];
            }
            #pragma unroll
            for (int cf = 0; cf < 2; ++cf) {
                int n = cw0 + cf * 16 + rsel;
                s16x8 bh = *(const s16x8*)&Wh[n * LDK2 + ksel];
                s16x8 bl = *(const s16x8*)&Wl[n * LDK2 + ksel];
                #pragma unroll
                for (int mf = 0; mf < 4; ++mf) {
                    acc[mf][cf] = __builtin_amdgcn_mfma_f32_16x16x32_bf16(ah4[mf], bh, acc[mf][cf], 0, 0, 0);
                    acc[mf][cf] = __builtin_amdgcn_mfma_f32_16x16x32_bf16(ah4[mf], bl, acc[mf][cf], 0, 0, 0);
                    acc[mf][cf] = __builtin_amdgcn_mfma_f32_16x16x32_bf16(al4[mf], bh, acc[mf][cf], 0, 0, 0);
                }
            }
            __syncthreads();
        }
    }
    // ---- final: out = relu(acc + bf), written once ----
    #pragma unroll
    for (int cf = 0; cf < 2; ++cf) {
        int col = cw0 + cf * 16 + ccol;
        float bb = bf[col];
        #pragma unroll
        for (int mf = 0; mf < 4; ++mf)
            #pragma unroll
            for (int ii = 0; ii < 4; ++ii) {
                int gm = m0 + mf * 16 + crow + ii;
                if (gm < N_NODES)
                    out[(size_t)gm * H_F + col] = fmaxf(acc[mf][cf][ii] + bb, 0.f);
            }
    }
}

extern "C" void kernel_launch(void* const* d_in, const int* in_sizes, int n_in,
                              void* d_out, int out_size, void* d_ws, size_t ws_size,
                              hipStream_t stream) {
    const int* ei = (const int*)d_in[0];
    const int* rows = ei;
    const int* cols = ei + N_EDGES;
    const float* feat = (const float*)d_in[1];
    const float* Ws = (const float*)d_in[2];
    const float* bs = (const float*)d_in[3];
    const float* Wf = (const float*)d_in[4];
    const float* bf = (const float*)d_in[5];
    float* out = (float*)d_out;

    // workspace layout (~85 MB)
    float* h0 = (float*)d_ws;                      // 4 x 4,800,000 f32
    float* h1 = h0 + (size_t)N_NODES * IN_F;
    float* h2 = h1 + (size_t)N_NODES * IN_F;
    float* h3 = h2 + (size_t)N_NODES * IN_F;
    ushort* WsTh = (ushort*)(h3 + (size_t)N_NODES * IN_F);  // 98,304 u16
    ushort* WsTl = WsTh + N_NIE * IN_F * H_F;
    ushort* WfTh = WsTl + N_NIE * IN_F * H_F;               // 262,144 u16
    ushort* WfTl = WfTh + N_NIE * H_F * H_F;
    float* dinv = (float*)(WfTl + N_NIE * H_F * H_F);       // 50,000 f32
    int* rowptr = (int*)(dinv + N_NODES);                   // 50,004 i32
    int* bsum = rowptr + 50004;                             // 256 i32
    int* boff = bsum + 256;                                 // 256 i32
    int2* cw = (int2*)(boff + 256);                         // 800,000 int2
    // CSR-build temporaries aliased into h1 (h1 written only later, by spmm)
    int* cnt = (int*)h1;
    int* cursor = cnt + N_NODES;

    hipMemsetAsync(cnt, 0, N_NODES * sizeof(int), stream);
    k_count<<<(N_EDGES / 2 + 255) / 256, 256, 0, stream>>>(rows, cols, cnt);
    k_scan1<<<SCAN_NB, 256, 0, stream>>>(cnt, rowptr, bsum);
    k_scan2<<<1, 256, 0, stream>>>(bsum, boff, rowptr);
    k_scan3<<<SCAN_NB, 256, 0, stream>>>(boff, cnt, rowptr, cursor, dinv);
    k_scatter<<<(N_EDGES + 255) / 256, 256, 0, stream>>>(rows, cols, dinv, cursor, cw);
    k_wsplit<<<(N_NIE * IN_F * H_F + 255) / 256, 256, 0, stream>>>(Ws, WsTh, WsTl, IN_F, H_F,
                                                                   N_NIE * IN_F * H_F);
    k_wsplit<<<(N_NIE * H_F * H_F + 255) / 256, 256, 0, stream>>>(Wf, WfTh, WfTl, H_F, H_F,
                                                                  N_NIE * H_F * H_F);
    k_norm<<<(N_NODES + 3) / 4, 256, 0, stream>>>(feat, h0);

    // hop chain first (h1..h3), then one fused GEMM pass
    k_spmm_csr<<<(N_NODES * 32 + 255) / 256, 256, 0, stream>>>(rowptr, cw, dinv, h0, h1);
    k_spmm_csr<<<(N_NODES * 32 + 255) / 256, 256, 0, stream>>>(rowptr, cw, dinv, h1, h2);
    k_spmm_csr<<<(N_NODES * 32 + 255) / 256, 256, 0, stream>>>(rowptr, cw, dinv, h2, h3);
    k_mega<<<(N_NODES + 63) / 64, 512, 0, stream>>>(h0, h1, h2, h3, WsTh, WsTl, bs,
                                                    WfTh, WfTl, bf, out);
}